// Round 1
// baseline (309.647 us; speedup 1.0000x reference)
//
#include <hip/hip_runtime.h>

// Problem constants (match reference)
#define B 32
#define S 32
#define N 128
#define U 64
#define E 2
#define NCLS 5

// Workspace layout (floats):
//   h: [B][N][U]      262144
//   p: [B][E][N][U]   524288
//   a: [B][N][U]      262144
// total 4 MB

// ---------------------------------------------------------------------------
// Gather the single relevant timestep per batch: h[b] = input[b, idx_b]
__global__ void k_init(const float* __restrict__ x, const int* __restrict__ lens,
                       float* __restrict__ h) {
    int b = blockIdx.x;
    int idx = lens[b] - 1;
    idx = idx < 0 ? 0 : (idx > S - 1 ? S - 1 : idx);
    const float4* src = (const float4*)(x + ((size_t)b * S + idx) * (N * U));
    float4* dst = (float4*)(h + (size_t)b * N * U);
    for (int i = threadIdx.x; i < N * U / 4; i += blockDim.x) dst[i] = src[i];
}

// ---------------------------------------------------------------------------
// p[b][e] = h[b] @ W_msg[l][e]   (used once at start; afterwards fused in k_update)
// grid = B*E*N/16 blocks of 256 (4 waves x 4 rows)
__global__ void k_p(const float* __restrict__ h, const float* __restrict__ Wmsg,
                    float* __restrict__ p, int l) {
    int wave = threadIdx.x >> 6, lane = threadIdx.x & 63;
    int row0 = blockIdx.x * 16 + wave * 4;  // in [0, B*E*N)
    int b = row0 >> 8;                      // E*N = 256 rows per batch
    int rem = row0 & 255;
    int e = rem >> 7;
    int n0 = rem & 127;
    const float* W = Wmsg + (size_t)(l * E + e) * U * U;
    float hv[4], acc[4] = {0.f, 0.f, 0.f, 0.f};
    for (int i = 0; i < 4; i++) hv[i] = h[((size_t)b * N + n0 + i) * U + lane];
    for (int u = 0; u < U; ++u) {
        float w = W[u * U + lane];
#pragma unroll
        for (int i = 0; i < 4; i++) acc[i] = fmaf(__shfl(hv[i], u, 64), w, acc[i]);
    }
    for (int i = 0; i < 4; i++)
        p[(((size_t)b * E + e) * N + n0 + i) * U + lane] = acc[i];
}

// ---------------------------------------------------------------------------
// a[b][n][:] = sum_e A[b,e,n,:] @ p[b][e] + b_msg[l]
// grid = B*N/16 = 256 blocks of 256; p[b] staged in LDS (64 KB)
__global__ void k_msg(const float* __restrict__ p, const float* __restrict__ A,
                      const float* __restrict__ bmsg, float* __restrict__ a, int l) {
    extern __shared__ float ps[];  // E*N*U floats
    int b = blockIdx.x >> 3;
    int n0 = (blockIdx.x & 7) * 16 + (threadIdx.x >> 6) * 4;
    int lane = threadIdx.x & 63;
    const float4* src = (const float4*)(p + (size_t)b * E * N * U);
    float4* dst4 = (float4*)ps;
    for (int i = threadIdx.x; i < E * N * U / 4; i += blockDim.x) dst4[i] = src[i];
    __syncthreads();
    float acc[4];
    float bm = bmsg[l * U + lane];
    for (int i = 0; i < 4; i++) acc[i] = bm;
    for (int e = 0; e < E; e++) {
        const float4* Ar[4];
        for (int i = 0; i < 4; i++)
            Ar[i] = (const float4*)(A + (((size_t)b * E + e) * N + n0 + i) * N);
        const float* pe = ps + e * N * U;
        for (int m4 = 0; m4 < N / 4; ++m4) {
            float4 av[4];
#pragma unroll
            for (int i = 0; i < 4; i++) av[i] = Ar[i][m4];
            float p0 = pe[(m4 * 4 + 0) * U + lane];
            float p1 = pe[(m4 * 4 + 1) * U + lane];
            float p2 = pe[(m4 * 4 + 2) * U + lane];
            float p3 = pe[(m4 * 4 + 3) * U + lane];
#pragma unroll
            for (int i = 0; i < 4; i++) {
                acc[i] = fmaf(av[i].x, p0, acc[i]);
                acc[i] = fmaf(av[i].y, p1, acc[i]);
                acc[i] = fmaf(av[i].z, p2, acc[i]);
                acc[i] = fmaf(av[i].w, p3, acc[i]);
            }
        }
    }
    for (int i = 0; i < 4; i++)
        a[((size_t)b * N + n0 + i) * U + lane] = acc[i];
}

// ---------------------------------------------------------------------------
// GRU-style gate update (row-local) + fused p for next step.
// grid = B*N/16 = 256 blocks of 256 (4 waves x 4 rows); lane = output column v
__global__ void k_update(float* __restrict__ h, const float* __restrict__ a_,
                         const float* __restrict__ Wg, const float* __restrict__ Ug,
                         const float* __restrict__ bg, const float* __restrict__ Wmsg,
                         float* __restrict__ p, int l, int lnext, int do_p) {
    int b = blockIdx.x >> 3;
    int n0 = (blockIdx.x & 7) * 16 + (threadIdx.x >> 6) * 4;
    int lane = threadIdx.x & 63;
    const float* Wg0 = Wg + (size_t)l * 3 * U * U;
    const float* Wg1 = Wg0 + U * U;
    const float* Wg2 = Wg1 + U * U;
    const float* Ug0 = Ug + (size_t)l * 3 * U * U;
    const float* Ug1 = Ug0 + U * U;
    const float* Ug2 = Ug1 + U * U;
    float av[4], hv[4], accz[4], accr[4], accc[4];
    float b0 = bg[(l * 3 + 0) * U + lane];
    float b1 = bg[(l * 3 + 1) * U + lane];
    float b2 = bg[(l * 3 + 2) * U + lane];
    for (int i = 0; i < 4; i++) {
        size_t row = ((size_t)b * N + n0 + i) * U + lane;
        av[i] = a_[row];
        hv[i] = h[row];
        accz[i] = b0; accr[i] = b1; accc[i] = b2;
    }
    for (int u = 0; u < U; ++u) {
        float w0 = Wg0[u * U + lane], w1 = Wg1[u * U + lane], w2 = Wg2[u * U + lane];
        float g0 = Ug0[u * U + lane], g1 = Ug1[u * U + lane];
#pragma unroll
        for (int i = 0; i < 4; i++) {
            float au = __shfl(av[i], u, 64), hu = __shfl(hv[i], u, 64);
            accz[i] = fmaf(au, w0, accz[i]);
            accz[i] = fmaf(hu, g0, accz[i]);
            accr[i] = fmaf(au, w1, accr[i]);
            accr[i] = fmaf(hu, g1, accr[i]);
            accc[i] = fmaf(au, w2, accc[i]);
        }
    }
    float rh[4];
    for (int i = 0; i < 4; i++) {
        float r = 1.f / (1.f + expf(-accr[i]));
        rh[i] = r * hv[i];
    }
    for (int u = 0; u < U; ++u) {
        float g2 = Ug2[u * U + lane];
#pragma unroll
        for (int i = 0; i < 4; i++) accc[i] = fmaf(__shfl(rh[i], u, 64), g2, accc[i]);
    }
    float hn[4];
    for (int i = 0; i < 4; i++) {
        float z = 1.f / (1.f + expf(-accz[i]));
        float c = tanhf(accc[i]);
        hn[i] = (1.f - z) * hv[i] + z * c;
        h[((size_t)b * N + n0 + i) * U + lane] = hn[i];
    }
    if (do_p) {
        const float* W0 = Wmsg + (size_t)(lnext * E + 0) * U * U;
        const float* W1 = Wmsg + (size_t)(lnext * E + 1) * U * U;
        float p0[4] = {0.f, 0.f, 0.f, 0.f}, p1[4] = {0.f, 0.f, 0.f, 0.f};
        for (int u = 0; u < U; ++u) {
            float w0 = W0[u * U + lane], w1 = W1[u * U + lane];
#pragma unroll
            for (int i = 0; i < 4; i++) {
                float hu = __shfl(hn[i], u, 64);
                p0[i] = fmaf(hu, w0, p0[i]);
                p1[i] = fmaf(hu, w1, p1[i]);
            }
        }
        for (int i = 0; i < 4; i++) {
            p[(((size_t)b * E + 0) * N + n0 + i) * U + lane] = p0[i];
            p[(((size_t)b * E + 1) * N + n0 + i) * U + lane] = p1[i];
        }
    }
}

// ---------------------------------------------------------------------------
// out[b][c] = max_n ( relu(h[b,n,:]) @ fc_w )[c] + fc_b[c]
// grid = B blocks of 256 (4 waves, 32 rows each)
__global__ void k_out(const float* __restrict__ h, const float* __restrict__ fcw,
                      const float* __restrict__ fcb, float* __restrict__ out) {
    __shared__ float red[4][NCLS];
    int b = blockIdx.x;
    int wave = threadIdx.x >> 6, lane = threadIdx.x & 63;
    float w[NCLS];
#pragma unroll
    for (int c = 0; c < NCLS; c++) w[c] = fcw[lane * NCLS + c];
    float mx[NCLS];
#pragma unroll
    for (int c = 0; c < NCLS; c++) mx[c] = -3.4e38f;
    for (int n = wave * 32; n < wave * 32 + 32; ++n) {
        float hv = h[((size_t)b * N + n) * U + lane];
        hv = hv > 0.f ? hv : 0.f;
        float lg[NCLS];
#pragma unroll
        for (int c = 0; c < NCLS; c++) lg[c] = hv * w[c];
#pragma unroll
        for (int off = 32; off; off >>= 1) {
#pragma unroll
            for (int c = 0; c < NCLS; c++) lg[c] += __shfl_xor(lg[c], off, 64);
        }
#pragma unroll
        for (int c = 0; c < NCLS; c++) mx[c] = fmaxf(mx[c], lg[c]);
    }
    if (lane == 0)
        for (int c = 0; c < NCLS; c++) red[wave][c] = mx[c];
    __syncthreads();
    if (threadIdx.x < NCLS) {
        float m = red[0][threadIdx.x];
        for (int wv = 1; wv < 4; ++wv) m = fmaxf(m, red[wv][threadIdx.x]);
        out[b * NCLS + threadIdx.x] = m + fcb[threadIdx.x];
    }
}

// ---------------------------------------------------------------------------
extern "C" void kernel_launch(void* const* d_in, const int* in_sizes, int n_in,
                              void* d_out, int out_size, void* d_ws, size_t ws_size,
                              hipStream_t stream) {
    const float* x    = (const float*)d_in[0];
    const int*   lens = (const int*)d_in[1];
    const float* A    = (const float*)d_in[2];
    const float* Wmsg = (const float*)d_in[3];
    const float* bmsg = (const float*)d_in[4];
    const float* Wg   = (const float*)d_in[5];
    const float* Ug   = (const float*)d_in[6];
    const float* bg   = (const float*)d_in[7];
    const float* fcw  = (const float*)d_in[8];
    const float* fcb  = (const float*)d_in[9];
    float* out = (float*)d_out;

    float* h = (float*)d_ws;                 // [B][N][U]
    float* p = h + (size_t)B * N * U;        // [B][E][N][U]
    float* a = p + (size_t)B * E * N * U;    // [B][N][U]

    k_init<<<B, 256, 0, stream>>>(x, lens, h);
    k_p<<<B * E * N / 16, 256, 0, stream>>>(h, Wmsg, p, 0);
    for (int step = 0; step < 6; ++step) {
        int l = step / 3;
        k_msg<<<B * N / 16, 256, E * N * U * 4, stream>>>(p, A, bmsg, a, l);
        int do_p = (step < 5) ? 1 : 0;
        int lnext = (step + 1) / 3;
        k_update<<<B * N / 16, 256, 0, stream>>>(h, a, Wg, Ug, bg, Wmsg, p, l, lnext, do_p);
    }
    k_out<<<B, 256, 0, stream>>>(h, fcw, fcb, out);
}

// Round 2
// 247.526 us; speedup vs baseline: 1.2510x; 1.2510x over previous
//
#include <hip/hip_runtime.h>

// Problem constants (match reference)
#define B 32
#define S 32
#define N 128
#define U 64
#define E 2
#define NCLS 5

// ---------------------------------------------------------------------------
// k_initp: gather the single relevant timestep per batch into h, and compute
// p0 = h @ W_msg[0][e] for both edge types. Row-local, so one launch.
// grid = 256 blocks x 256 thr; block owns 16 (b,n) rows (4 waves x 4 rows).
__global__ void k_initp(const float* __restrict__ x, const int* __restrict__ lens,
                        const float* __restrict__ Wmsg,
                        float* __restrict__ h, float* __restrict__ p) {
    int wave = threadIdx.x >> 6, lane = threadIdx.x & 63;
    int b = blockIdx.x >> 3;
    int n0 = (blockIdx.x & 7) * 16 + wave * 4;
    int idx = lens[b] - 1;
    idx = idx < 0 ? 0 : (idx > S - 1 ? S - 1 : idx);
    const float* src = x + ((size_t)(b * S + idx) * N) * U;
    float hv[4];
#pragma unroll
    for (int i = 0; i < 4; i++) {
        hv[i] = src[(size_t)(n0 + i) * U + lane];
        h[((size_t)b * N + n0 + i) * U + lane] = hv[i];
    }
    const float* W0 = Wmsg;          // l=0, e=0
    const float* W1 = Wmsg + U * U;  // l=0, e=1
    float p0[4] = {0.f, 0.f, 0.f, 0.f}, p1[4] = {0.f, 0.f, 0.f, 0.f};
    for (int u = 0; u < U; ++u) {
        float w0 = W0[u * U + lane], w1 = W1[u * U + lane];
#pragma unroll
        for (int i = 0; i < 4; i++) {
            float hu = __shfl(hv[i], u, 64);
            p0[i] = fmaf(hu, w0, p0[i]);
            p1[i] = fmaf(hu, w1, p1[i]);
        }
    }
#pragma unroll
    for (int i = 0; i < 4; i++) {
        p[(((size_t)b * E + 0) * N + n0 + i) * U + lane] = p0[i];
        p[(((size_t)b * E + 1) * N + n0 + i) * U + lane] = p1[i];
    }
}

// ---------------------------------------------------------------------------
// k_step: one full GGNN propagation step, fused:
//   a = sum_e A_e @ p_e + b_msg          (needs ALL rows of p -> LDS stage)
//   z,r,c gates; h' = (1-z)h + z c       (row-local)
//   p' = h' @ W_msg[lnext][e]            (row-local, for next step)
//   optional: per-block partial of max_n relu(h')@fc_w   (last step)
// p is double-buffered across launches (pin != pout) because other blocks of
// the same b may still be reading pin while we write pout.
// grid = 256 blocks x 512 thr; block owns 16 (b,n) rows (8 waves x 2 rows).
__global__ __launch_bounds__(512) void k_step(
    const float* __restrict__ pin, float* __restrict__ pout,
    float* __restrict__ h, const float* __restrict__ A,
    const float* __restrict__ bmsg, const float* __restrict__ Wg,
    const float* __restrict__ Ug, const float* __restrict__ bg,
    const float* __restrict__ Wmsg, const float* __restrict__ fcw,
    float* __restrict__ partial,
    int l, int lnext, int do_p, int do_out) {
    extern __shared__ float ps[];  // E*N*U floats = 64 KB (reused for out-reduce)
    int tid = threadIdx.x;
    int wave = tid >> 6, lane = tid & 63;
    int b = blockIdx.x >> 3;
    int n0 = (blockIdx.x & 7) * 16 + wave * 2;

    // ---- stage p[b] (all E*N rows) into LDS: 4096 float4 over 512 threads
    {
        const float4* s4 = (const float4*)(pin + (size_t)b * E * N * U);
        float4* d4 = (float4*)ps;
#pragma unroll
        for (int i = 0; i < 8; i++) d4[tid + i * 512] = s4[tid + i * 512];
    }
    __syncthreads();

    // ---- message aggregation for our 2 rows
    float bm = bmsg[l * U + lane];
    float av[2] = {bm, bm};
    for (int e = 0; e < E; ++e) {
        const float4* A0 = (const float4*)(A + (((size_t)b * E + e) * N + n0 + 0) * N);
        const float4* A1 = (const float4*)(A + (((size_t)b * E + e) * N + n0 + 1) * N);
        const float* pe = ps + e * N * U;
        for (int m4 = 0; m4 < N / 4; ++m4) {
            float4 a0 = A0[m4], a1 = A1[m4];
            float q0 = pe[(m4 * 4 + 0) * U + lane];
            float q1 = pe[(m4 * 4 + 1) * U + lane];
            float q2 = pe[(m4 * 4 + 2) * U + lane];
            float q3 = pe[(m4 * 4 + 3) * U + lane];
            av[0] = fmaf(a0.x, q0, av[0]); av[0] = fmaf(a0.y, q1, av[0]);
            av[0] = fmaf(a0.z, q2, av[0]); av[0] = fmaf(a0.w, q3, av[0]);
            av[1] = fmaf(a1.x, q0, av[1]); av[1] = fmaf(a1.y, q1, av[1]);
            av[1] = fmaf(a1.z, q2, av[1]); av[1] = fmaf(a1.w, q3, av[1]);
        }
    }

    // ---- gate matmuls (lane = output column v)
    float hv[2];
    hv[0] = h[((size_t)b * N + n0 + 0) * U + lane];
    hv[1] = h[((size_t)b * N + n0 + 1) * U + lane];
    float b0 = bg[(l * 3 + 0) * U + lane];
    float b1 = bg[(l * 3 + 1) * U + lane];
    float b2 = bg[(l * 3 + 2) * U + lane];
    float accz[2] = {b0, b0}, accr[2] = {b1, b1}, accc[2] = {b2, b2};
    const float* Wg0 = Wg + (size_t)l * 3 * U * U;
    const float* Wg1 = Wg0 + U * U;
    const float* Wg2 = Wg1 + U * U;
    const float* Ug0 = Ug + (size_t)l * 3 * U * U;
    const float* Ug1 = Ug0 + U * U;
    const float* Ug2 = Ug1 + U * U;
    for (int u = 0; u < U; ++u) {
        float w0 = Wg0[u * U + lane], w1 = Wg1[u * U + lane], w2 = Wg2[u * U + lane];
        float g0 = Ug0[u * U + lane], g1 = Ug1[u * U + lane];
#pragma unroll
        for (int i = 0; i < 2; i++) {
            float au = __shfl(av[i], u, 64), hu = __shfl(hv[i], u, 64);
            accz[i] = fmaf(au, w0, accz[i]);
            accz[i] = fmaf(hu, g0, accz[i]);
            accr[i] = fmaf(au, w1, accr[i]);
            accr[i] = fmaf(hu, g1, accr[i]);
            accc[i] = fmaf(au, w2, accc[i]);
        }
    }
    float rh[2];
#pragma unroll
    for (int i = 0; i < 2; i++) {
        float r = 1.f / (1.f + __expf(-accr[i]) * 0.f + expf(-accr[i]) * 1.f);
        rh[i] = r * hv[i];
    }
    for (int u = 0; u < U; ++u) {
        float g2 = Ug2[u * U + lane];
#pragma unroll
        for (int i = 0; i < 2; i++) accc[i] = fmaf(__shfl(rh[i], u, 64), g2, accc[i]);
    }
    float hn[2];
#pragma unroll
    for (int i = 0; i < 2; i++) {
        float z = 1.f / (1.f + expf(-accz[i]));
        float c = tanhf(accc[i]);
        hn[i] = (1.f - z) * hv[i] + z * c;
        h[((size_t)b * N + n0 + i) * U + lane] = hn[i];
    }

    // ---- fused p' = h' @ W_msg[lnext] for next step
    if (do_p) {
        const float* W0 = Wmsg + (size_t)(lnext * E + 0) * U * U;
        const float* W1 = Wmsg + (size_t)(lnext * E + 1) * U * U;
        float p0[2] = {0.f, 0.f}, p1[2] = {0.f, 0.f};
        for (int u = 0; u < U; ++u) {
            float w0 = W0[u * U + lane], w1 = W1[u * U + lane];
#pragma unroll
            for (int i = 0; i < 2; i++) {
                float hu = __shfl(hn[i], u, 64);
                p0[i] = fmaf(hu, w0, p0[i]);
                p1[i] = fmaf(hu, w1, p1[i]);
            }
        }
#pragma unroll
        for (int i = 0; i < 2; i++) {
            pout[(((size_t)b * E + 0) * N + n0 + i) * U + lane] = p0[i];
            pout[(((size_t)b * E + 1) * N + n0 + i) * U + lane] = p1[i];
        }
    }

    // ---- fused classification partial (last step only):
    // partial[blockIdx] = max over our 16 rows of relu(h') @ fc_w
    if (do_out) {
        float lg[2][NCLS];
#pragma unroll
        for (int i = 0; i < 2; i++) {
            float rv = hn[i] > 0.f ? hn[i] : 0.f;
#pragma unroll
            for (int c = 0; c < NCLS; c++) lg[i][c] = rv * fcw[lane * NCLS + c];
        }
#pragma unroll
        for (int off = 32; off; off >>= 1) {
#pragma unroll
            for (int i = 0; i < 2; i++)
#pragma unroll
                for (int c = 0; c < NCLS; c++) lg[i][c] += __shfl_xor(lg[i][c], off, 64);
        }
        float mx[NCLS];
#pragma unroll
        for (int c = 0; c < NCLS; c++) mx[c] = fmaxf(lg[0][c], lg[1][c]);
        __syncthreads();  // everyone done reading ps; safe to reuse as reduce buf
        if (lane == 0) {
#pragma unroll
            for (int c = 0; c < NCLS; c++) ps[wave * NCLS + c] = mx[c];
        }
        __syncthreads();
        if (tid < NCLS) {
            float m = ps[tid];
            for (int w = 1; w < 8; ++w) m = fmaxf(m, ps[w * NCLS + tid]);
            partial[(size_t)blockIdx.x * NCLS + tid] = m;
        }
    }
}

// ---------------------------------------------------------------------------
// k_final: out[b][c] = max over 8 block-partials + fc_b
__global__ void k_final(const float* __restrict__ partial, const float* __restrict__ fcb,
                        float* __restrict__ out) {
    int b = blockIdx.x, c = threadIdx.x;
    if (c < NCLS) {
        float m = -3.4e38f;
        for (int j = 0; j < 8; ++j) m = fmaxf(m, partial[(size_t)(b * 8 + j) * NCLS + c]);
        out[b * NCLS + c] = m + fcb[c];
    }
}

// ---------------------------------------------------------------------------
extern "C" void kernel_launch(void* const* d_in, const int* in_sizes, int n_in,
                              void* d_out, int out_size, void* d_ws, size_t ws_size,
                              hipStream_t stream) {
    const float* x    = (const float*)d_in[0];
    const int*   lens = (const int*)d_in[1];
    const float* A    = (const float*)d_in[2];
    const float* Wmsg = (const float*)d_in[3];
    const float* bmsg = (const float*)d_in[4];
    const float* Wg   = (const float*)d_in[5];
    const float* Ug   = (const float*)d_in[6];
    const float* bg   = (const float*)d_in[7];
    const float* fcw  = (const float*)d_in[8];
    const float* fcb  = (const float*)d_in[9];
    float* out = (float*)d_out;

    float* h       = (float*)d_ws;                   // [B][N][U]
    float* pA      = h + (size_t)B * N * U;          // [B][E][N][U]
    float* pB      = pA + (size_t)B * E * N * U;     // [B][E][N][U]
    float* partial = pB + (size_t)B * E * N * U;     // [256][NCLS]

    const size_t smem = (size_t)E * N * U * sizeof(float);  // 64 KB

    k_initp<<<256, 256, 0, stream>>>(x, lens, Wmsg, h, pA);
    float* bufs[2] = {pA, pB};
    for (int step = 0; step < 6; ++step) {
        int l = step / 3;
        int lnext = (step + 1) / 3;
        int do_p = (step < 5) ? 1 : 0;
        int do_out = (step == 5) ? 1 : 0;
        k_step<<<256, 512, smem, stream>>>(bufs[step & 1], bufs[(step + 1) & 1], h, A,
                                           bmsg, Wg, Ug, bg, Wmsg, fcw, partial,
                                           l, lnext, do_p, do_out);
    }
    k_final<<<B, 64, 0, stream>>>(partial, fcb, out);
}